// Round 10
// baseline (149.533 us; speedup 1.0000x reference)
//
#include <hip/hip_runtime.h>
#include <hip/hip_bf16.h>

#define NV   128

constexpr float EPSV = 1e-5f;
constexpr float TWO_PI_F = 6.28318530717958647692f;
constexpr float DELTA_F  = 0.39269908169872414f;   // f32(2pi/16 in f64)

typedef __attribute__((ext_vector_type(8))) short bfrag8;        // 8 bf16
typedef __attribute__((ext_vector_type(4))) float facc4;         // 4 f32
typedef __attribute__((ext_vector_type(4))) unsigned int uvec4;  // 4 u32

__device__ __forceinline__ unsigned short f2bf(float x) {
    return __bfloat16_as_ushort(__float2bfloat16(x));
}

// ---------------------------------------------------------------------------
// Pre-pack W into bf16 B-fragment order (unchanged, passed rounds 3/4/9):
// wf[fid*512 + lane*8 + j] = bf16(W[w][g][o]),  fid = (w*5+ot)*3 + s,
//   o = ot*16 + (lane&15),  g = s*32 + (lane>>4)*8 + j  (0 if g >= 80)
// ---------------------------------------------------------------------------
__global__ void pack_w(const float* __restrict__ Wc, unsigned short* __restrict__ wf) {
    int t = blockIdx.x * blockDim.x + threadIdx.x;
    if (t >= 75 * 64) return;
    const int fid = t >> 6, l = t & 63;
    const int s  = fid % 3, wo = fid / 3;
    const int ot = wo % 5,  w  = wo / 5;
    const int o  = ot * 16 + (l & 15);
    const int g0 = s * 32 + (l >> 4) * 8;
    bfrag8 fv;
    #pragma unroll
    for (int j = 0; j < 8; ++j) {
        const int g = g0 + j;
        const float val = (g < 80) ? Wc[(w * 80 + g) * 80 + o] : 0.0f;
        fv[j] = (short)f2bf(val);
    }
    *(bfrag8*)&wf[(size_t)fid * 512 + l * 8] = fv;
}

// ---------------------------------------------------------------------------
// Same math as r9 (passed, absmax 0.0156). Changes are SCHEDULING only:
//  - gather software-pipelined: double-buffered bu[2][4]; rotation i+1's 32
//    ds_read_u16 issue before rotation i's MFMAs -> lgkm latency hidden
//  - per-element index hoisted: kv unpacked once, e <- (e+15)&15 per rotation,
//    address = Pb + 2e (1 lshl_add)
//  - B3 W-fragments prefetched into regs before the barrier (latency hides
//    under barrier wait); B3 is then pure LDS+MFMA
// LDS 38.5 KB -> 4 blocks/CU (unchanged).
// ---------------------------------------------------------------------------
__global__ __launch_bounds__(256, 4)
void lsres_kernel(const float* __restrict__ feat,
                  const float* __restrict__ rho,
                  const float* __restrict__ theta,
                  const float* __restrict__ mask,
                  const float* __restrict__ mu_rho,
                  const float* __restrict__ mu_theta,
                  const float* __restrict__ sigma_rho,
                  const float* __restrict__ sigma_theta,
                  const float* __restrict__ Wc,
                  const float* __restrict__ bc,
                  const unsigned short* __restrict__ wf,   // may be null
                  float* __restrict__ out)
{
    __shared__ __align__(16) unsigned short fa_t[40 * 128];     // 10 KB, XOR-swizzled
    __shared__ __align__(16) unsigned short Trev[6144];         // 12 KB, 96B pitch
    __shared__ __align__(16) unsigned short desc_all[80 * 104]; // 16.25 KB
    __shared__ unsigned char K_pack[NV];                        // 128 B

    const int tid  = threadIdx.x;
    const int lane = tid & 63;
    const int wq   = tid >> 6;
    const int site = blockIdx.x;

    // ---------------- Phase A0: zero desc pad cols (g=80..95) ----------------
    {
        unsigned int* dz = (unsigned int*)desc_all;
        for (int i = tid; i < 640; i += 256) {
            const int row = i >> 3, col = i & 7;
            dz[row * 52 + 40 + col] = 0;
        }
    }

    // ---------------- Phase A1: reversed theta table ----------------
    {
        const int v = tid >> 1, h = tid & 1;
        const float th = theta[site * NV + v];
        int K = 0;
        #pragma unroll
        for (int k = 0; k < 16; ++k) {
            const float ck = (float)(k * 0.39269908169872414);  // same wrap rule as r3/r9
            K += (th + ck < TWO_PI_F) ? 1 : 0;
        }
        if (h == 0) K_pack[v] = (unsigned char)K;
        const float st0 = sigma_theta[0];
        const float nit = -1.0f / (st0 * st0 + EPSV);
        uvec4 w0, w1;
        #pragma unroll
        for (int p = 0; p < 8; ++p) {
            float e[2];
            #pragma unroll
            for (int z = 0; z < 2; ++z) {
                const int j = h * 16 + p * 2 + z;
                const float nf = (float)(K - j);                // Trev[j] = exp((th+(K-j)D)^2 * nit)
                const float x  = fmaf(nf, DELTA_F, th);
                e[z] = __expf(x * x * nit);
            }
            const unsigned int pk = (unsigned int)f2bf(e[0]) |
                                    ((unsigned int)f2bf(e[1]) << 16);
            if (p < 4) w0[p] = pk; else w1[p - 4] = pk;
        }
        char* rowp = (char*)Trev + v * 96 + ((v >> 3) & 1) * 32 + h * 32;
        *(uvec4*)rowp        = w0;
        *(uvec4*)(rowp + 16) = w1;
    }

    // ---------------- Phase A2: rho gaussians * mask * feat ----------------
    if (tid < NV) {
        const int v = tid;
        const float rv = rho[site * NV + v];
        const float mv = mask[site * NV + v];
        float f[6];
        #pragma unroll
        for (int c = 0; c < 5; ++c) f[c] = feat[(site * NV + v) * 5 + c];
        f[5] = 1.0f;
        #pragma unroll
        for (int r = 0; r < 5; ++r) {
            const float mr  = mu_rho[r * 16];
            const float sr  = sigma_rho[r * 16];
            const float inv = 1.0f / (sr * sr + EPSV);
            const float d   = rv - mr;
            const float rg  = __expf(-d * d * inv) * mv;
            #pragma unroll
            for (int c = 0; c < 6; ++c) {
                const int cr = r * 8 + c;
                const int byte = cr * 256 + ((v * 2) ^ ((cr & 7) << 4));
                fa_t[byte >> 1] = f2bf(rg * f[c]);
            }
        }
        // rows r*8+{6,7} uninitialized: read only as independent MFMA A rows,
        // whose C rows are discarded (c>=6 never used by normalize)
    }
    __syncthreads();

    // ---------------- per-wave setup ----------------
    const int q = lane >> 4, t = lane & 15;

    bfrag8 afrag[3][4];
    #pragma unroll
    for (int m = 0; m < 2; ++m)
        #pragma unroll
        for (int s = 0; s < 4; ++s) {
            const int cr = m * 16 + t;
            const int byte = cr * 256 + ((s * 64 + q * 16) ^ ((cr & 7) << 4));
            afrag[m][s] = *(const bfrag8*)((const char*)fa_t + byte);
        }
    #pragma unroll
    for (int s = 0; s < 4; ++s) {
        if (t < 8) {
            const int cr = 32 + t;
            const int byte = cr * 256 + ((s * 64 + q * 16) ^ ((cr & 7) << 4));
            afrag[2][s] = *(const bfrag8*)((const char*)fa_t + byte);
        } else {
            afrag[2][s] = (bfrag8){0, 0, 0, 0, 0, 0, 0, 0};
        }
    }

    // hoisted gather state: e_[s][j] rotation index, Pb[s][j] address base
    const int lbase = q * 768 + (q & 1) * 32 + 2 * t;   // 96B pitch + stagger + t
    int e_[4][8], Pb[4][8];
    {
        unsigned int Kpk[4][2];
        #pragma unroll
        for (int s = 0; s < 4; ++s) {
            Kpk[s][0] = *(const unsigned int*)&K_pack[s * 32 + q * 8];
            Kpk[s][1] = *(const unsigned int*)&K_pack[s * 32 + q * 8 + 4];
        }
        const int einit = 15 - wq * 4;                  // e for k = wq*4
        #pragma unroll
        for (int s = 0; s < 4; ++s)
            #pragma unroll
            for (int j = 0; j < 8; ++j) {
                const int kv = (Kpk[s][j >> 2] >> ((j & 3) * 8)) & 0xff;
                e_[s][j] = (kv + einit) & 15;
                Pb[s][j] = lbase + s * 3072 + j * 96 + 2;
            }
    }

    uvec4 bu[2][4];
    auto gather = [&](uvec4 (&BU)[4]) {
        #pragma unroll
        for (int s = 0; s < 4; ++s) {
            #pragma unroll
            for (int jp = 0; jp < 4; ++jp) {
                const unsigned int v0 = *(const unsigned short*)
                    ((const char*)Trev + (Pb[s][2 * jp]     + 2 * e_[s][2 * jp]));
                const unsigned int v1 = *(const unsigned short*)
                    ((const char*)Trev + (Pb[s][2 * jp + 1] + 2 * e_[s][2 * jp + 1]));
                BU[s][jp] = v0 | (v1 << 16);
            }
        }
    };
    gather(bu[0]);   // prologue: rotation wq*4+0 in flight

    // ---------------- rotation loop (pipelined, barrier-free) ----------------
    #pragma unroll
    for (int i = 0; i < 4; ++i) {
        const int cur = i & 1;
        // prefetch rotation i+1 (reads issue before this rotation's MFMAs)
        if (i < 3) {
            #pragma unroll
            for (int s = 0; s < 4; ++s)
                #pragma unroll
                for (int j = 0; j < 8; ++j)
                    e_[s][j] = (e_[s][j] + 15) & 15;    // e -= 1 mod 16
            gather(bu[cur ^ 1]);
        }

        const int k = wq * 4 + i;
        facc4 acc[3];
        #pragma unroll
        for (int m = 0; m < 3; ++m) acc[m] = (facc4){0.f, 0.f, 0.f, 0.f};
        #pragma unroll
        for (int s = 0; s < 4; ++s) {
            const bfrag8 b = __builtin_bit_cast(bfrag8, bu[cur][s]);
            acc[0] = __builtin_amdgcn_mfma_f32_16x16x32_bf16(afrag[0][s], b, acc[0], 0, 0, 0);
            acc[1] = __builtin_amdgcn_mfma_f32_16x16x32_bf16(afrag[1][s], b, acc[1], 0, 0, 0);
            acc[2] = __builtin_amdgcn_mfma_f32_16x16x32_bf16(afrag[2][s], b, acc[2], 0, 0, 0);
        }

        // in-register normalize -> desc_all (bf16)  [verbatim r9]
        const int cbase = (q & 1) * 4;
        #pragma unroll
        for (int m = 0; m < 3; ++m) {
            const float den = __shfl(acc[m][1], ((q | 1) << 4) | t, 64);
            const float rcp = __builtin_amdgcn_rcpf(den + EPSV);
            const int r = 2 * m + (q >> 1);
            if (r < 5) {
                #pragma unroll
                for (int jj = 0; jj < 4; ++jj) {
                    const int c = cbase + jj;                 // = w when < 5
                    if (c < 5) {
                        const float val = acc[m][jj] * rcp;
                        desc_all[(c * 16 + k) * 104 + r * 16 + t] = f2bf(val);
                    }
                }
            }
        }
    }

    // prefetch B3 W-fragments (fly during the barrier wait)
    bfrag8 wfreg[7][3];
    if (wf) {
        #pragma unroll
        for (int uu = 0; uu < 7; ++uu) {
            const int u = wq + uu * 4;
            if (u < 25) {
                #pragma unroll
                for (int s3 = 0; s3 < 3; ++s3)
                    wfreg[uu][s3] = *(const bfrag8*)
                        &wf[((size_t)(u * 3 + s3)) * 512 + lane * 8];
            }
        }
    }
    __syncthreads();

    // ---------------- B3: cf[k][o] = desc[w] @ W[w], max over k ----------------
    #pragma unroll
    for (int uu = 0; uu < 7; ++uu) {
        const int u = wq + uu * 4;
        if (u < 25) {
            const int w  = u / 5;
            const int ot = u - w * 5;
            const int o  = ot * 16 + t;
            facc4 acc = {0.f, 0.f, 0.f, 0.f};
            #pragma unroll
            for (int s = 0; s < 3; ++s) {
                const bfrag8 a = *(const bfrag8*)
                    &desc_all[(w * 16 + t) * 104 + s * 32 + q * 8];
                bfrag8 bf;
                if (wf) {
                    bf = wfreg[uu][s];
                } else {
                    #pragma unroll
                    for (int j = 0; j < 8; ++j) {
                        const int g = s * 32 + q * 8 + j;
                        const float val = (g < 80) ? Wc[(w * 80 + g) * 80 + o] : 0.0f;
                        bf[j] = (short)f2bf(val);
                    }
                }
                acc = __builtin_amdgcn_mfma_f32_16x16x32_bf16(a, bf, acc, 0, 0, 0);
            }
            float mx = fmaxf(fmaxf(acc[0], acc[1]), fmaxf(acc[2], acc[3]));
            mx = fmaxf(mx, __shfl_xor(mx, 16, 64));
            mx = fmaxf(mx, __shfl_xor(mx, 32, 64));
            if (lane < 16) {
                out[(size_t)site * 400 + w * 80 + o] = mx + bc[w * 80 + o];
            }
        }
    }
}

extern "C" void kernel_launch(void* const* d_in, const int* in_sizes, int n_in,
                              void* d_out, int out_size, void* d_ws, size_t ws_size,
                              hipStream_t stream) {
    const float* feat        = (const float*)d_in[0];
    const float* rho         = (const float*)d_in[1];
    const float* theta       = (const float*)d_in[2];
    const float* mask        = (const float*)d_in[3];
    const float* mu_rho      = (const float*)d_in[4];
    const float* mu_theta    = (const float*)d_in[5];
    const float* sigma_rho   = (const float*)d_in[6];
    const float* sigma_theta = (const float*)d_in[7];
    const float* Wc          = (const float*)d_in[8];
    const float* bc          = (const float*)d_in[9];
    float* outp              = (float*)d_out;

    unsigned short* wfp = nullptr;
    if (ws_size >= (size_t)75 * 512 * sizeof(unsigned short)) {
        wfp = (unsigned short*)d_ws;
        pack_w<<<19, 256, 0, stream>>>(Wc, wfp);
    }

    const int sites = in_sizes[1] / NV;   // B*S = 4096
    lsres_kernel<<<sites, 256, 0, stream>>>(feat, rho, theta, mask,
                                            mu_rho, mu_theta, sigma_rho, sigma_theta,
                                            Wc, bc, wfp, outp);
}